// Round 7
// baseline (774.062 us; speedup 1.0000x reference)
//
#include <hip/hip_runtime.h>
#include <math.h>

typedef unsigned short u16;
typedef unsigned int u32;
typedef __attribute__((ext_vector_type(4))) unsigned short u16x4;
typedef __attribute__((ext_vector_type(8))) short bf16x8;
typedef __attribute__((ext_vector_type(4))) float f32x4;

#define B_ 4
#define S_ 2048
#define D_ 1024
#define H_ 16
#define NT (B_*S_)
#define DFF 4096

static __device__ __forceinline__ float bf2f(u16 u) {
    return __uint_as_float(((u32)u) << 16);
}
static __device__ __forceinline__ u16 f2bf(float f) {
    u32 u = __float_as_uint(f);
    u32 r = (u + 0x7fffu + ((u >> 16) & 1u)) >> 16;
    return (u16)r;
}
// async 16B/lane global->LDS (LDS dest = wave-uniform base + lane*16)
static __device__ __forceinline__ void gload_lds16(const void* g, void* l) {
    __builtin_amdgcn_global_load_lds(
        (const __attribute__((address_space(1))) void*)g,
        (__attribute__((address_space(3))) void*)l, 16, 0, 0);
}

// ------------------------------------------------- transpose fp32 -> bf16
// batched x4 (same RxC for all): z picks src/dst
__global__ void transpose_f2b4(const float* __restrict__ s0, const float* __restrict__ s1,
                               const float* __restrict__ s2, const float* __restrict__ s3,
                               u16* __restrict__ d0, u16* __restrict__ d1,
                               u16* __restrict__ d2, u16* __restrict__ d3,
                               int R, int C) {
    const float* in = s0; u16* out = d0;
    if (blockIdx.z == 1) { in = s1; out = d1; }
    else if (blockIdx.z == 2) { in = s2; out = d2; }
    else if (blockIdx.z == 3) { in = s3; out = d3; }
    __shared__ float t[32][33];
    int c0 = blockIdx.x * 32, r0 = blockIdx.y * 32;
    int x = threadIdx.x, y = threadIdx.y;
    #pragma unroll
    for (int i = 0; i < 4; i++)
        t[y + i*8][x] = in[(long)(r0 + y + i*8) * C + c0 + x];
    __syncthreads();
    #pragma unroll
    for (int i = 0; i < 4; i++)
        out[(long)(c0 + y + i*8) * R + r0 + x] = f2bf(t[x][y + i*8]);
}

__global__ void transpose_f2b(const float* __restrict__ in, u16* __restrict__ out,
                              int R, int C) {
    __shared__ float t[32][33];
    int c0 = blockIdx.x * 32, r0 = blockIdx.y * 32;
    int x = threadIdx.x, y = threadIdx.y;
    #pragma unroll
    for (int i = 0; i < 4; i++)
        t[y + i*8][x] = in[(long)(r0 + y + i*8) * C + c0 + x];
    __syncthreads();
    #pragma unroll
    for (int i = 0; i < 4; i++)
        out[(long)(c0 + y + i*8) * R + r0 + x] = f2bf(t[x][y + i*8]);
}

// V bf16 [B*S][D] -> Vt bf16 [B*H][64][S]. grid (S/32, 2, B*H), block (32,8)
__global__ void transpose_v(const u16* __restrict__ V, u16* __restrict__ Vt) {
    __shared__ u16 t[32][33];
    int z = blockIdx.z; int b = z >> 4, h = z & 15;
    int s0 = blockIdx.x * 32, d0 = blockIdx.y * 32;
    int x = threadIdx.x, y = threadIdx.y;
    const u16* in = V + ((long)b * S_ + s0) * D_ + h * 64 + d0;
    #pragma unroll
    for (int i = 0; i < 4; i++)
        t[y + i*8][x] = in[(long)(y + i*8) * D_ + x];
    __syncthreads();
    u16* out = Vt + ((long)z * 64 + d0) * S_ + s0;
    #pragma unroll
    for (int i = 0; i < 4; i++)
        out[(long)(y + i*8) * S_ + x] = t[x][y + i*8];
}

// ------------------------------------------------- layernorm (fp32 in, bf16 out)
__global__ __launch_bounds__(256) void ln_kernel(
    const float* __restrict__ X, const float* __restrict__ alpha,
    const float* __restrict__ beta, u16* __restrict__ Y) {
    int row = blockIdx.x, tid = threadIdx.x;
    float4 xv = ((const float4*)(X + (long)row * D_))[tid];
    float v[4] = {xv.x, xv.y, xv.z, xv.w};
    float s = 0.f, ss = 0.f;
    #pragma unroll
    for (int i = 0; i < 4; i++) { s += v[i]; ss += v[i]*v[i]; }
    #pragma unroll
    for (int off = 32; off >= 1; off >>= 1) {
        s += __shfl_xor(s, off);
        ss += __shfl_xor(ss, off);
    }
    __shared__ float red[8];
    __shared__ float stats[2];
    int w = tid >> 6;
    if ((tid & 63) == 0) { red[w] = s; red[4 + w] = ss; }
    __syncthreads();
    if (tid == 0) {
        float S = red[0] + red[1] + red[2] + red[3];
        float SS = red[4] + red[5] + red[6] + red[7];
        float mean = S * (1.f / D_);
        float var = SS * (1.f / D_) - mean * mean;
        stats[0] = mean; stats[1] = rsqrtf(var + 1e-5f);
    }
    __syncthreads();
    float mean = stats[0], rstd = stats[1];
    float4 av = ((const float4*)alpha)[tid];
    float4 bv = ((const float4*)beta)[tid];
    u16x4 o;
    o[0] = f2bf((v[0] - mean) * rstd * av.x + bv.x);
    o[1] = f2bf((v[1] - mean) * rstd * av.y + bv.y);
    o[2] = f2bf((v[2] - mean) * rstd * av.z + bv.z);
    o[3] = f2bf((v[3] - mean) * rstd * av.w + bv.w);
    *(u16x4*)(Y + (long)row * D_ + tid * 4) = o;
}

// ------------------------------------------------- GEMM (bf16 A, bf16 B^T)
// m97 recipe: unpadded [row][64] LDS tiles staged via global_load_lds x16.
// mode 0: bf16 store; 1: fp32 acc+resid; 2: bf16 gelu(acc+bias); 3: fp32 acc+bias+resid
#define BM 128
#define BN 128
#define BK 64

__global__ __launch_bounds__(256, 2) void gemm_bt(
    const u16* __restrict__ A,
    const u16* __restrict__ Bt0, const u16* __restrict__ Bt1, const u16* __restrict__ Bt2,
    void* __restrict__ C0, void* __restrict__ C1, void* __restrict__ C2,
    int M, int N, int K, int mode,
    const float* __restrict__ bias, const float* __restrict__ resid) {
    const u16* Bt = Bt0; void* C = C0;
    if (blockIdx.z == 1) { Bt = Bt1; C = C1; }
    else if (blockIdx.z == 2) { Bt = Bt2; C = C2; }

    __shared__ __align__(16) u16 Asm[BM * BK];
    __shared__ __align__(16) u16 Bsm[BN * BK];

    int tid = threadIdx.x;
    int lane = tid & 63, wave = tid >> 6;
    int l15 = lane & 15, quad = lane >> 4;
    int wm = wave & 1, wn = wave >> 1;
    long tm0 = (long)blockIdx.y * BM, tn0 = (long)blockIdx.x * BN;

    int srow = lane >> 3;          // 0..7 within chunk
    int scol = (lane & 7) * 8;     // u16 col offset

    f32x4 acc[4][4] = {};

    for (int k0 = 0; k0 < K; k0 += BK) {
        __syncthreads();
        #pragma unroll
        for (int c = 0; c < 4; c++) {
            int chunk = wave * 4 + c;          // 0..15
            int row = chunk * 8 + srow;        // 0..127
            gload_lds16(&A[(tm0 + row) * (long)K + k0 + scol], &Asm[chunk * 512]);
            gload_lds16(&Bt[(tn0 + row) * (long)K + k0 + scol], &Bsm[chunk * 512]);
        }
        __syncthreads();   // drains vmcnt(0): LDS tiles complete
        #pragma unroll
        for (int ks = 0; ks < 2; ks++) {
            bf16x8 af[4], bfm[4];
            #pragma unroll
            for (int mt = 0; mt < 4; mt++)
                af[mt] = *(const bf16x8*)&Asm[(wm*64 + mt*16 + l15) * BK + ks*32 + quad*8];
            #pragma unroll
            for (int nt = 0; nt < 4; nt++)
                bfm[nt] = *(const bf16x8*)&Bsm[(wn*64 + nt*16 + l15) * BK + ks*32 + quad*8];
            #pragma unroll
            for (int mt = 0; mt < 4; mt++)
                #pragma unroll
                for (int nt = 0; nt < 4; nt++)
                    acc[mt][nt] = __builtin_amdgcn_mfma_f32_16x16x32_bf16(
                        af[mt], bfm[nt], acc[mt][nt], 0, 0, 0);
        }
    }

    #pragma unroll
    for (int mt = 0; mt < 4; mt++) {
        #pragma unroll
        for (int nt = 0; nt < 4; nt++) {
            #pragma unroll
            for (int i = 0; i < 4; i++) {
                long r = tm0 + wm*64 + mt*16 + quad*4 + i;
                long cn = tn0 + wn*64 + nt*16 + l15;
                long idx = r * N + cn;
                float val = acc[mt][nt][i];
                if (mode == 0) {
                    ((u16*)C)[idx] = f2bf(val);
                } else if (mode == 1) {
                    ((float*)C)[idx] = val + resid[idx];
                } else if (mode == 2) {
                    val += bias[cn];
                    val = 0.5f * val * (1.0f + erff(val * 0.70710678118654752f));
                    ((u16*)C)[idx] = f2bf(val);
                } else {
                    ((float*)C)[idx] = val + bias[cn] + resid[idx];
                }
            }
        }
    }
}

// ------------------------------------------------- attention
// Wave-autonomous, zero barriers. 16-row q-tiles, paired (t, 127-t) so every
// wave runs exactly 33-34 k-iterations. Grid (bh=64, 16) -> 1024 blocks,
// 4 blocks/CU (4 waves/SIMD); all blocks of one head land on one XCD
// (linear id % 8 == bh % 8) so K/V stay L2-resident (round-6 verified).
// Computes S^T (swapped MFMA operands): C-layout then gives each lane 4
// CONSECUTIVE k values -> P round-trip is 4x ds_write_b64 + 2x ds_read_b128
// instead of 32 scalar writes. Pack via v_perm_b32 (truncating bf16: P in
// [0,1], error <= 2^-8, inside absmax headroom). Fixed-max exp2 softmax;
// denominator from all-ones MFMA.
#define LDPq 72   // P row stride in u16 (144B: 8B- and 16B-aligned accesses ok)

__global__ __launch_bounds__(256, 4) void attn_kernel(
    const u16* __restrict__ Q, const u16* __restrict__ Kg, const u16* __restrict__ Vt,
    const int* __restrict__ mask, u16* __restrict__ O) {
    __shared__ __align__(16) u16 Psm[4][16 * LDPq];
    int tid = threadIdx.x;
    int lane = tid & 63, wave = tid >> 6;
    int l15 = lane & 15, quad = lane >> 4;
    int bh = blockIdx.x; int b = bh >> 4, h = bh & 15;
    int j = wave * 16 + blockIdx.y;     // 0..63
    long tokBase = (long)b * S_;
    const float SCL = 0.125f * 1.4426950408889634f;  // exp2 domain
    const float MMAX = 20.0f;                        // fixed softmax shift

    const bf16x8 ones = {16256,16256,16256,16256,16256,16256,16256,16256}; // bf16 1.0
    u16* Pw = Psm[wave];
    const int* mb = mask + b * S_;

    #pragma unroll
    for (int half = 0; half < 2; half++) {
        int t = half ? (127 - j) : j;   // q-tile 0..127 (16 rows each)
        int q0 = t * 16;

        const u16* qptr = Q + (tokBase + q0 + l15) * D_ + h * 64;
        bf16x8 aq0 = *(const bf16x8*)(qptr + quad * 8);
        bf16x8 aq1 = *(const bf16x8*)(qptr + 32 + quad * 8);

        f32x4 o[4] = {};
        f32x4 lacc = {};
        int qg = q0 + l15;
        int ktiles = t / 4 + 1;

        for (int kt = 0; kt < ktiles; kt++) {
            int k0 = kt * 64;
            bf16x8 kb[4][2], vb[4][2];
            #pragma unroll
            for (int st = 0; st < 4; st++) {
                const u16* kp = Kg + (tokBase + k0 + st*16 + l15) * D_ + h * 64;
                kb[st][0] = *(const bf16x8*)(kp + quad * 8);
                kb[st][1] = *(const bf16x8*)(kp + 32 + quad * 8);
            }
            #pragma unroll
            for (int dt = 0; dt < 4; dt++) {
                const u16* vp = Vt + ((long)bh * 64 + dt*16 + l15) * S_ + k0;
                vb[dt][0] = *(const bf16x8*)(vp + quad * 8);
                vb[dt][1] = *(const bf16x8*)(vp + 32 + quad * 8);
            }

            // S^T tiles: rows = k (quad*4+i), cols = q (l15)
            f32x4 s[4] = {};
            #pragma unroll
            for (int st = 0; st < 4; st++) {
                s[st] = __builtin_amdgcn_mfma_f32_16x16x32_bf16(kb[st][0], aq0, s[st], 0,0,0);
                s[st] = __builtin_amdgcn_mfma_f32_16x16x32_bf16(kb[st][1], aq1, s[st], 0,0,0);
            }

            #pragma unroll
            for (int st = 0; st < 4; st++) {
                int4 m4 = *(const int4*)&mb[k0 + st*16 + quad*4];
                int kbase = k0 + st*16 + quad*4;
                float p[4];
                p[0] = (kbase + 0 <= qg && m4.x != 0) ? exp2f(fmaf(s[st][0], SCL, -MMAX)) : 0.f;
                p[1] = (kbase + 1 <= qg && m4.y != 0) ? exp2f(fmaf(s[st][1], SCL, -MMAX)) : 0.f;
                p[2] = (kbase + 2 <= qg && m4.z != 0) ? exp2f(fmaf(s[st][2], SCL, -MMAX)) : 0.f;
                p[3] = (kbase + 3 <= qg && m4.w != 0) ? exp2f(fmaf(s[st][3], SCL, -MMAX)) : 0.f;
                // pack 2 f32 -> dword of 2 bf16 (truncate) via byte-perm
                u32 pk0 = __builtin_amdgcn_perm(__float_as_uint(p[1]), __float_as_uint(p[0]), 0x07060302u);
                u32 pk1 = __builtin_amdgcn_perm(__float_as_uint(p[3]), __float_as_uint(p[2]), 0x07060302u);
                uint2 w2 = {pk0, pk1};
                *(uint2*)&Pw[l15 * LDPq + st*16 + quad*4] = w2;   // ds_write_b64
            }
            // same-wave P write -> read ordering (DS ops in-order per wave)
            asm volatile("s_waitcnt lgkmcnt(0)" ::: "memory");
            bf16x8 ap0 = *(const bf16x8*)&Pw[l15 * LDPq + quad*8];
            bf16x8 ap1 = *(const bf16x8*)&Pw[l15 * LDPq + 32 + quad*8];

            #pragma unroll
            for (int dt = 0; dt < 4; dt++) {
                o[dt] = __builtin_amdgcn_mfma_f32_16x16x32_bf16(ap0, vb[dt][0], o[dt], 0,0,0);
                o[dt] = __builtin_amdgcn_mfma_f32_16x16x32_bf16(ap1, vb[dt][1], o[dt], 0,0,0);
            }
            lacc = __builtin_amdgcn_mfma_f32_16x16x32_bf16(ap0, ones, lacc, 0,0,0);
            lacc = __builtin_amdgcn_mfma_f32_16x16x32_bf16(ap1, ones, lacc, 0,0,0);
        }

        #pragma unroll
        for (int i = 0; i < 4; i++) {
            float inv = 1.f / lacc[i];
            long r = tokBase + q0 + quad*4 + i;
            #pragma unroll
            for (int dt = 0; dt < 4; dt++)
                O[r * D_ + h*64 + dt*16 + l15] = f2bf(o[dt][i] * inv);
        }
    }
}

// ------------------------------------------------- launch
extern "C" void kernel_launch(void* const* d_in, const int* in_sizes, int n_in,
                              void* d_out, int out_size, void* d_ws, size_t ws_size,
                              hipStream_t stream) {
    const float* x    = (const float*)d_in[0];
    const int*   am   = (const int*)d_in[1];
    const float* ln1a = (const float*)d_in[2];
    const float* ln1b = (const float*)d_in[3];
    const float* ln2a = (const float*)d_in[4];
    const float* ln2b = (const float*)d_in[5];
    const float* wq   = (const float*)d_in[6];
    const float* wk   = (const float*)d_in[7];
    const float* wv   = (const float*)d_in[8];
    const float* wo   = (const float*)d_in[9];
    const float* w1   = (const float*)d_in[10];
    const float* b1   = (const float*)d_in[11];
    const float* w2   = (const float*)d_in[12];
    const float* b2   = (const float*)d_in[13];
    float* out = (float*)d_out;

    // Workspace: 72 MB, liveness-overlapped 16MB slots.
    char* ws = (char*)d_ws;
    const size_t MB16 = (size_t)16 * 1024 * 1024;
    u16* y1      = (u16*)(ws + 0 * MB16);   // LN1 out -> y2 (LN2 out)
    u16* q       = (u16*)(ws + 1 * MB16);   // q -> w1t/w2t
    u16* k       = (u16*)(ws + 2 * MB16);   // k -> h (slots 2+3)
    u16* v       = (u16*)(ws + 3 * MB16);   // v -> ctx -> h(hi)
    u16* wqt     = (u16*)(ws + 4 * MB16 + 0 * (size_t)D_ * D_ * 2);
    u16* wkt     = (u16*)(ws + 4 * MB16 + 1 * (size_t)D_ * D_ * 2);
    u16* wvt     = (u16*)(ws + 4 * MB16 + 2 * (size_t)D_ * D_ * 2);
    u16* wot     = (u16*)(ws + 4 * MB16 + 3 * (size_t)D_ * D_ * 2);
    u16* y2      = y1;                       // after QKV
    u16* w1t     = q;                        // after attn (8 MB)
    u16* w2t     = q + (size_t)D_ * DFF;     // after attn (8 MB)
    u16* h_full  = k;                        // after Wo GEMM: 32 MB (slots 2+3)
    u16* ctx     = v;                        // after transpose_v
    u16*   vt  = (u16*)d_out;                // d_out scratch; dead after attn
    float* x1f = out;                        // x + ctx@Wo

    dim3 tb(32, 8);
    transpose_f2b4<<<dim3(D_/32, D_/32, 4), tb, 0, stream>>>(
        wq, wk, wv, wo, wqt, wkt, wvt, wot, D_, D_);

    ln_kernel<<<NT, 256, 0, stream>>>(x, ln1a, ln1b, y1);

    gemm_bt<<<dim3(D_/BN, NT/BM, 3), 256, 0, stream>>>(
        y1, wqt, wkt, wvt, q, k, v, NT, D_, D_, 0, nullptr, nullptr);

    transpose_v<<<dim3(S_/32, 2, B_*H_), tb, 0, stream>>>(v, vt);

    attn_kernel<<<dim3(B_*H_, 16), 256, 0, stream>>>(q, k, vt, am, ctx);

    gemm_bt<<<dim3(D_/BN, NT/BM, 1), 256, 0, stream>>>(
        ctx, wot, wot, wot, x1f, x1f, x1f, NT, D_, D_, 1, nullptr, x);

    transpose_f2b<<<dim3(DFF/32, D_/32), tb, 0, stream>>>(w1, w1t, D_, DFF);
    transpose_f2b<<<dim3(D_/32, DFF/32), tb, 0, stream>>>(w2, w2t, DFF, D_);

    ln_kernel<<<NT, 256, 0, stream>>>(x1f, ln2a, ln2b, y2);

    // FFN, unchunked (h: 32MB in slots 2+3)
    gemm_bt<<<dim3(DFF/BN, NT/BM, 1), 256, 0, stream>>>(
        y2, w1t, w1t, w1t, h_full, h_full, h_full, NT, DFF, D_, 2, b1, nullptr);
    gemm_bt<<<dim3(D_/BN, NT/BM, 1), 256, 0, stream>>>(
        h_full, w2t, w2t, w2t, out, out, out, NT, D_, DFF, 3, b2, x1f);
}